// Round 1
// baseline (1425.333 us; speedup 1.0000x reference)
//
#include <hip/hip_runtime.h>
#include <hip/hip_bf16.h>

#define H_DIM 1024
#define I_DIM 2816
#define NE 8
#define T_TOK 8192
#define BM 128
#define BN 128
#define BK 64
#define LDSS 72   // padded LDS row stride in shorts (64 + 8)

// ws byte offsets
#define WS_ROUTE_CNT 0                 // int[8]
#define WS_CURSOR    32                // int[8]
#define WS_PO        64                // int[16]
#define WS_TOP1      128               // float[8]
#define WS_PSUM      160               // float[8]
#define WS_RECIDX    256               // int[8192]
#define WS_RECW0     33024             // float[8192]
#define WS_RECW1     65792             // float[8192]
#define WS_TOKID     98560             // int[17408]
#define WS_TOKW      168192            // float[17408]
#define WS_ACT       262144            // short(bf16)[17408*2816]

typedef __attribute__((ext_vector_type(8))) short short8;
typedef __attribute__((ext_vector_type(4))) float f32x4;

static __device__ __forceinline__ short f2bf(float f) {
  return (short)__builtin_bit_cast(unsigned short, (__bf16)f);
}

static __device__ __forceinline__ short8 pack8(const float* __restrict__ p) {
  float4 a = *(const float4*)p;
  float4 b = *(const float4*)(p + 4);
  short8 v;
  v[0] = f2bf(a.x); v[1] = f2bf(a.y); v[2] = f2bf(a.z); v[3] = f2bf(a.w);
  v[4] = f2bf(b.x); v[5] = f2bf(b.y); v[6] = f2bf(b.z); v[7] = f2bf(b.w);
  return v;
}

// ---------------- router: logits -> softmax -> top2 + aux accumulators ----
__global__ __launch_bounds__(256) void k_router(const float* __restrict__ x,
                                                const float* __restrict__ gw,
                                                char* __restrict__ ws) {
  int tid = threadIdx.x;
  int lane = tid & 63;
  int wv = tid >> 6;
  int t = blockIdx.x * 4 + wv;

  float acc[NE];
#pragma unroll
  for (int e = 0; e < NE; ++e) acc[e] = 0.f;
  const float* xr = x + (size_t)t * H_DIM;
#pragma unroll
  for (int k = 0; k < H_DIM / 64; ++k) {
    float xv = xr[k * 64 + lane];
#pragma unroll
    for (int e = 0; e < NE; ++e) acc[e] += xv * gw[e * H_DIM + k * 64 + lane];
  }
#pragma unroll
  for (int e = 0; e < NE; ++e) {
#pragma unroll
    for (int off = 32; off; off >>= 1) acc[e] += __shfl_xor(acc[e], off);
  }

  __shared__ float s_ps[NE], s_c1[NE];
  __shared__ int s_rc[NE];
  if (tid < NE) { s_ps[tid] = 0.f; s_c1[tid] = 0.f; s_rc[tid] = 0; }
  __syncthreads();

  int* recIdx = (int*)(ws + WS_RECIDX);
  float* recW0 = (float*)(ws + WS_RECW0);
  float* recW1 = (float*)(ws + WS_RECW1);

  if (lane == 0) {
    float mx = acc[0];
#pragma unroll
    for (int e = 1; e < NE; ++e) mx = fmaxf(mx, acc[e]);
    float p[NE], s = 0.f;
#pragma unroll
    for (int e = 0; e < NE; ++e) { p[e] = expf(acc[e] - mx); s += p[e]; }
    float inv = 1.f / s;
#pragma unroll
    for (int e = 0; e < NE; ++e) p[e] *= inv;
    int i0 = 0;
#pragma unroll
    for (int e = 1; e < NE; ++e) if (p[e] > p[i0]) i0 = e;
    int i1 = (i0 == 0) ? 1 : 0;
#pragma unroll
    for (int e = 0; e < NE; ++e) if (e != i0 && p[e] > p[i1]) i1 = e;
    float w0 = p[i0], w1 = p[i1];
    float sm = fmaxf(w0 + w1, 1e-8f);
    w0 /= sm; w1 /= sm;
    recIdx[t] = i0 | (i1 << 8);
    recW0[t] = w0;
    recW1[t] = w1;
    atomicAdd(&s_c1[i0], 1.f);
#pragma unroll
    for (int e = 0; e < NE; ++e) atomicAdd(&s_ps[e], p[e]);
    atomicAdd(&s_rc[i0], 1);
    atomicAdd(&s_rc[i1], 1);
  }
  __syncthreads();
  if (tid < NE) {
    atomicAdd((float*)(ws + WS_PSUM) + tid, s_ps[tid]);
    atomicAdd((float*)(ws + WS_TOP1) + tid, s_c1[tid]);
    atomicAdd((int*)(ws + WS_ROUTE_CNT) + tid, s_rc[tid]);
  }
}

// ---------------- offsets (128-padded) + aux loss -------------------------
__global__ void k_offsets(char* __restrict__ ws, float* __restrict__ out_aux) {
  if (threadIdx.x == 0) {
    int* rc = (int*)(ws + WS_ROUTE_CNT);
    int* po = (int*)(ws + WS_PO);
    int acc = 0;
    for (int e = 0; e < NE; ++e) {
      po[e] = acc;
      acc += ((rc[e] + BM - 1) / BM) * BM;
    }
    po[NE] = acc;
    float* c1 = (float*)(ws + WS_TOP1);
    float* ps = (float*)(ws + WS_PSUM);
    float aux = 0.f;
    for (int e = 0; e < NE; ++e)
      aux += (c1[e] / (float)T_TOK) * (ps[e] / (float)T_TOK);
    out_aux[0] = aux * (float)NE;
  }
}

// ---------------- assign: fill per-expert compact segments ----------------
__global__ __launch_bounds__(256) void k_assign(char* __restrict__ ws) {
  int t = blockIdx.x * 256 + threadIdx.x;
  if (t >= T_TOK) return;
  int* recIdx = (int*)(ws + WS_RECIDX);
  float* recW0 = (float*)(ws + WS_RECW0);
  float* recW1 = (float*)(ws + WS_RECW1);
  int* cursor = (int*)(ws + WS_CURSOR);
  int* po = (int*)(ws + WS_PO);
  int* tokid = (int*)(ws + WS_TOKID);
  float* tokw = (float*)(ws + WS_TOKW);

  int rec = recIdx[t];
  int e0 = rec & 255, e1 = (rec >> 8) & 255;
  int p0 = atomicAdd(&cursor[e0], 1);
  tokid[po[e0] + p0] = t;
  tokw[po[e0] + p0] = recW0[t];
  int p1 = atomicAdd(&cursor[e1], 1);
  tokid[po[e1] + p1] = t;
  tokw[po[e1] + p1] = recW1[t];
}

// ---------------- FFN1: act = silu(x@Wg^T) * (x@Wu^T) ---------------------
__global__ __launch_bounds__(256, 2) void k_ffn1(const float* __restrict__ x,
                                                 const float* __restrict__ wg,
                                                 const float* __restrict__ wu,
                                                 char* __restrict__ ws) {
  int mt = blockIdx.x, nt = blockIdx.y, e = blockIdx.z;
  const int* rc = (const int*)(ws + WS_ROUTE_CNT);
  int cnt = rc[e];
  if (mt * BM >= cnt) return;
  const int* po = (const int*)(ws + WS_PO);
  int poe = po[e];
  const int* tokid = (const int*)(ws + WS_TOKID);
  short* act = (short*)(ws + WS_ACT);

  __shared__ __align__(16) short As[BM * LDSS];
  __shared__ __align__(16) short Bg[BN * LDSS];
  __shared__ __align__(16) short Bu[BN * LDSS];

  int tid = threadIdx.x;
  int lane = tid & 63, wv = tid >> 6;
  int wr = (wv >> 1) * 64, wc = (wv & 1) * 64;
  int fr = lane & 15, kq = (lane >> 4) * 8;

  const float* wgb = wg + (size_t)e * I_DIM * H_DIM;
  const float* wub = wu + (size_t)e * I_DIM * H_DIM;

  // precompute staging sources
  const float* asrc[4];
  const float* bsg[4];
  const float* bsu[4];
  int loff[4];
#pragma unroll
  for (int it = 0; it < 4; ++it) {
    int slot = it * 256 + tid;
    int r = slot >> 3;
    int kg = (slot & 7) * 8;
    loff[it] = r * LDSS + kg;
    int rowg = mt * BM + r;
    asrc[it] = (rowg < cnt) ? (x + (size_t)tokid[poe + rowg] * H_DIM + kg) : nullptr;
    bsg[it] = wgb + (size_t)(nt * BN + r) * H_DIM + kg;
    bsu[it] = wub + (size_t)(nt * BN + r) * H_DIM + kg;
  }

  f32x4 accg[4][4], accu[4][4];
  f32x4 z4 = {0.f, 0.f, 0.f, 0.f};
#pragma unroll
  for (int m = 0; m < 4; ++m)
#pragma unroll
    for (int n = 0; n < 4; ++n) { accg[m][n] = z4; accu[m][n] = z4; }

  for (int kk = 0; kk < H_DIM; kk += BK) {
#pragma unroll
    for (int it = 0; it < 4; ++it) {
      short8 av = 0;
      if (asrc[it]) av = pack8(asrc[it] + kk);
      *(short8*)&As[loff[it]] = av;
      *(short8*)&Bg[loff[it]] = pack8(bsg[it] + kk);
      *(short8*)&Bu[loff[it]] = pack8(bsu[it] + kk);
    }
    __syncthreads();
#pragma unroll
    for (int ks = 0; ks < 2; ++ks) {
      short8 af[4];
#pragma unroll
      for (int m = 0; m < 4; ++m)
        af[m] = *(const short8*)&As[(wr + m * 16 + fr) * LDSS + ks * 32 + kq];
#pragma unroll
      for (int n = 0; n < 4; ++n) {
        short8 bgf = *(const short8*)&Bg[(wc + n * 16 + fr) * LDSS + ks * 32 + kq];
        short8 buf_ = *(const short8*)&Bu[(wc + n * 16 + fr) * LDSS + ks * 32 + kq];
#pragma unroll
        for (int m = 0; m < 4; ++m) {
          accg[m][n] = __builtin_amdgcn_mfma_f32_16x16x32_bf16(af[m], bgf, accg[m][n], 0, 0, 0);
          accu[m][n] = __builtin_amdgcn_mfma_f32_16x16x32_bf16(af[m], buf_, accu[m][n], 0, 0, 0);
        }
      }
    }
    __syncthreads();
  }

  // epilogue: silu(g)*u -> bf16 act
#pragma unroll
  for (int m = 0; m < 4; ++m)
#pragma unroll
    for (int n = 0; n < 4; ++n)
#pragma unroll
      for (int j = 0; j < 4; ++j) {
        int row = wr + m * 16 + (lane >> 4) * 4 + j;
        int col = nt * BN + wc + n * 16 + fr;
        float g = accg[m][n][j];
        float u = accu[m][n][j];
        float a = g / (1.f + expf(-g)) * u;
        act[(size_t)(poe + mt * BM + row) * I_DIM + col] = f2bf(a);
      }
}

// ---------------- FFN2: y = act @ Wd^T, scaled scatter-add ----------------
__global__ __launch_bounds__(256, 2) void k_ffn2(const float* __restrict__ wd,
                                                 float* __restrict__ out,
                                                 char* __restrict__ ws) {
  int mt = blockIdx.x, nt = blockIdx.y, e = blockIdx.z;
  const int* rc = (const int*)(ws + WS_ROUTE_CNT);
  int cnt = rc[e];
  if (mt * BM >= cnt) return;
  const int* po = (const int*)(ws + WS_PO);
  int poe = po[e];
  const int* tokid = (const int*)(ws + WS_TOKID);
  const float* tokw = (const float*)(ws + WS_TOKW);
  const short* act = (const short*)(ws + WS_ACT);

  __shared__ __align__(16) short As[BM * LDSS];
  __shared__ __align__(16) short Bd[BN * LDSS];

  int tid = threadIdx.x;
  int lane = tid & 63, wv = tid >> 6;
  int wr = (wv >> 1) * 64, wc = (wv & 1) * 64;
  int fr = lane & 15, kq = (lane >> 4) * 8;

  const float* wdb = wd + (size_t)e * H_DIM * I_DIM;

  const short* asrc[4];
  const float* bsd[4];
  int loff[4];
#pragma unroll
  for (int it = 0; it < 4; ++it) {
    int slot = it * 256 + tid;
    int r = slot >> 3;
    int kg = (slot & 7) * 8;
    loff[it] = r * LDSS + kg;
    asrc[it] = act + (size_t)(poe + mt * BM + r) * I_DIM + kg;
    bsd[it] = wdb + (size_t)(nt * BN + r) * I_DIM + kg;
  }

  f32x4 acc[4][4];
  f32x4 z4 = {0.f, 0.f, 0.f, 0.f};
#pragma unroll
  for (int m = 0; m < 4; ++m)
#pragma unroll
    for (int n = 0; n < 4; ++n) acc[m][n] = z4;

  for (int kk = 0; kk < I_DIM; kk += BK) {
#pragma unroll
    for (int it = 0; it < 4; ++it) {
      *(short8*)&As[loff[it]] = *(const short8*)(asrc[it] + kk);
      *(short8*)&Bd[loff[it]] = pack8(bsd[it] + kk);
    }
    __syncthreads();
#pragma unroll
    for (int ks = 0; ks < 2; ++ks) {
      short8 af[4];
#pragma unroll
      for (int m = 0; m < 4; ++m)
        af[m] = *(const short8*)&As[(wr + m * 16 + fr) * LDSS + ks * 32 + kq];
#pragma unroll
      for (int n = 0; n < 4; ++n) {
        short8 bdf = *(const short8*)&Bd[(wc + n * 16 + fr) * LDSS + ks * 32 + kq];
#pragma unroll
        for (int m = 0; m < 4; ++m)
          acc[m][n] = __builtin_amdgcn_mfma_f32_16x16x32_bf16(af[m], bdf, acc[m][n], 0, 0, 0);
      }
    }
    __syncthreads();
  }

#pragma unroll
  for (int m = 0; m < 4; ++m)
#pragma unroll
    for (int n = 0; n < 4; ++n)
#pragma unroll
      for (int j = 0; j < 4; ++j) {
        int row = wr + m * 16 + (lane >> 4) * 4 + j;
        int rg = mt * BM + row;
        if (rg < cnt) {
          int tok = tokid[poe + rg];
          float wgt = tokw[poe + rg];
          int col = nt * BN + wc + n * 16 + fr;
          atomicAdd(&out[(size_t)tok * H_DIM + col], wgt * acc[m][n][j]);
        }
      }
}

extern "C" void kernel_launch(void* const* d_in, const int* in_sizes, int n_in,
                              void* d_out, int out_size, void* d_ws, size_t ws_size,
                              hipStream_t stream) {
  const float* x  = (const float*)d_in[0];
  const float* gw = (const float*)d_in[1];
  const float* wg = (const float*)d_in[2];
  const float* wu = (const float*)d_in[3];
  const float* wd = (const float*)d_in[4];
  float* out = (float*)d_out;
  char* ws = (char*)d_ws;

  hipMemsetAsync(ws, 0, 256, stream);
  hipMemsetAsync(d_out, 0, (size_t)out_size * sizeof(float), stream);

  k_router<<<T_TOK / 4, 256, 0, stream>>>(x, gw, ws);
  k_offsets<<<1, 64, 0, stream>>>(ws, out + (size_t)T_TOK * H_DIM);
  k_assign<<<T_TOK / 256, 256, 0, stream>>>(ws);
  k_ffn1<<<dim3(64, I_DIM / BN, NE), 256, 0, stream>>>(x, wg, wu, ws);
  k_ffn2<<<dim3(64, H_DIM / BN, NE), 256, 0, stream>>>(wd, out, ws);
}

// Round 2
// 1046.278 us; speedup vs baseline: 1.3623x; 1.3623x over previous
//
#include <hip/hip_runtime.h>
#include <hip/hip_bf16.h>

#define H_DIM 1024
#define I_DIM 2816
#define NE 8
#define T_TOK 8192
#define RMAX 17408
#define BM 128
#define BN 128
#define BK 64
#define MT_MAX 64

// control ws offsets (bytes)
#define WS_ROUTE_CNT 0
#define WS_CURSOR    32
#define WS_PO        64
#define WS_TOP1      128
#define WS_PSUM      160
#define WS_RECIDX    256
#define WS_RECW0     33024
#define WS_RECW1     65792
#define WS_TOKID     98560
#define WS_TOKW      168192

constexpr size_t WS_XG  = 1ull << 20;
constexpr size_t XG_SZ  = (size_t)RMAX * H_DIM * 2;
constexpr size_t W_SZ   = (size_t)NE * I_DIM * H_DIM * 2;
constexpr size_t WS_WGB = WS_XG + XG_SZ;
constexpr size_t WS_WUB = WS_WGB + W_SZ;
constexpr size_t WS_WDB = WS_WUB + W_SZ;
constexpr size_t WS_ACT = WS_WDB + W_SZ;   // bf16[RMAX][I_DIM]

typedef __attribute__((ext_vector_type(8))) short short8;
typedef __attribute__((ext_vector_type(4))) float f32x4;

#define GLOAD16(g, l) __builtin_amdgcn_global_load_lds( \
    (const __attribute__((address_space(1))) void*)(g), \
    (__attribute__((address_space(3))) void*)(l), 16, 0, 0)

static __device__ __forceinline__ short f2bf(float f) {
  return (short)__builtin_bit_cast(unsigned short, (__bf16)f);
}

static __device__ __forceinline__ short8 pack8(const float* __restrict__ p) {
  float4 a = *(const float4*)p;
  float4 b = *(const float4*)(p + 4);
  short8 v;
  v[0] = f2bf(a.x); v[1] = f2bf(a.y); v[2] = f2bf(a.z); v[3] = f2bf(a.w);
  v[4] = f2bf(b.x); v[5] = f2bf(b.y); v[6] = f2bf(b.z); v[7] = f2bf(b.w);
  return v;
}

// ---------------- router ---------------------------------------------------
__global__ __launch_bounds__(256) void k_router(const float* __restrict__ x,
                                                const float* __restrict__ gw,
                                                char* __restrict__ ws) {
  int tid = threadIdx.x;
  int lane = tid & 63;
  int wv = tid >> 6;
  int t = blockIdx.x * 4 + wv;

  float acc[NE];
#pragma unroll
  for (int e = 0; e < NE; ++e) acc[e] = 0.f;
  const float* xr = x + (size_t)t * H_DIM;
#pragma unroll
  for (int k = 0; k < H_DIM / 64; ++k) {
    float xv = xr[k * 64 + lane];
#pragma unroll
    for (int e = 0; e < NE; ++e) acc[e] += xv * gw[e * H_DIM + k * 64 + lane];
  }
#pragma unroll
  for (int e = 0; e < NE; ++e) {
#pragma unroll
    for (int off = 32; off; off >>= 1) acc[e] += __shfl_xor(acc[e], off);
  }

  __shared__ float s_ps[NE], s_c1[NE];
  __shared__ int s_rc[NE];
  if (tid < NE) { s_ps[tid] = 0.f; s_c1[tid] = 0.f; s_rc[tid] = 0; }
  __syncthreads();

  int* recIdx = (int*)(ws + WS_RECIDX);
  float* recW0 = (float*)(ws + WS_RECW0);
  float* recW1 = (float*)(ws + WS_RECW1);

  if (lane == 0) {
    float mx = acc[0];
#pragma unroll
    for (int e = 1; e < NE; ++e) mx = fmaxf(mx, acc[e]);
    float p[NE], s = 0.f;
#pragma unroll
    for (int e = 0; e < NE; ++e) { p[e] = expf(acc[e] - mx); s += p[e]; }
    float inv = 1.f / s;
#pragma unroll
    for (int e = 0; e < NE; ++e) p[e] *= inv;
    int i0 = 0;
#pragma unroll
    for (int e = 1; e < NE; ++e) if (p[e] > p[i0]) i0 = e;
    int i1 = (i0 == 0) ? 1 : 0;
#pragma unroll
    for (int e = 0; e < NE; ++e) if (e != i0 && p[e] > p[i1]) i1 = e;
    float w0 = p[i0], w1 = p[i1];
    float sm = fmaxf(w0 + w1, 1e-8f);
    w0 /= sm; w1 /= sm;
    recIdx[t] = i0 | (i1 << 8);
    recW0[t] = w0;
    recW1[t] = w1;
    atomicAdd(&s_c1[i0], 1.f);
#pragma unroll
    for (int e = 0; e < NE; ++e) atomicAdd(&s_ps[e], p[e]);
    atomicAdd(&s_rc[i0], 1);
    atomicAdd(&s_rc[i1], 1);
  }
  __syncthreads();
  if (tid < NE) {
    atomicAdd((float*)(ws + WS_PSUM) + tid, s_ps[tid]);
    atomicAdd((float*)(ws + WS_TOP1) + tid, s_c1[tid]);
    atomicAdd((int*)(ws + WS_ROUTE_CNT) + tid, s_rc[tid]);
  }
}

// ---------------- offsets + aux --------------------------------------------
__global__ void k_offsets(char* __restrict__ ws, float* __restrict__ out_aux) {
  if (threadIdx.x == 0) {
    int* rc = (int*)(ws + WS_ROUTE_CNT);
    int* po = (int*)(ws + WS_PO);
    int acc = 0;
    for (int e = 0; e < NE; ++e) {
      po[e] = acc;
      acc += ((rc[e] + BM - 1) / BM) * BM;
    }
    po[NE] = acc;
    float* c1 = (float*)(ws + WS_TOP1);
    float* ps = (float*)(ws + WS_PSUM);
    float aux = 0.f;
    for (int e = 0; e < NE; ++e)
      aux += (c1[e] / (float)T_TOK) * (ps[e] / (float)T_TOK);
    out_aux[0] = aux * (float)NE;
  }
}

// ---------------- assign ----------------------------------------------------
__global__ __launch_bounds__(256) void k_assign(char* __restrict__ ws) {
  int t = blockIdx.x * 256 + threadIdx.x;
  if (t >= T_TOK) return;
  int* recIdx = (int*)(ws + WS_RECIDX);
  float* recW0 = (float*)(ws + WS_RECW0);
  float* recW1 = (float*)(ws + WS_RECW1);
  int* cursor = (int*)(ws + WS_CURSOR);
  int* po = (int*)(ws + WS_PO);
  int* tokid = (int*)(ws + WS_TOKID);
  float* tokw = (float*)(ws + WS_TOKW);

  int rec = recIdx[t];
  int e0 = rec & 255, e1 = (rec >> 8) & 255;
  int p0 = atomicAdd(&cursor[e0], 1);
  tokid[po[e0] + p0] = t;
  tokw[po[e0] + p0] = recW0[t];
  int p1 = atomicAdd(&cursor[e1], 1);
  tokid[po[e1] + p1] = t;
  tokw[po[e1] + p1] = recW1[t];
}

// ---------------- gather x -> bf16 permuted (zero-padded) -------------------
__global__ __launch_bounds__(256) void k_gather(const float* __restrict__ x,
                                                char* __restrict__ ws) {
  const int* po = (const int*)(ws + WS_PO);
  const int* rc = (const int*)(ws + WS_ROUTE_CNT);
  const int* tokid = (const int*)(ws + WS_TOKID);
  short* xg = (short*)(ws + WS_XG);
  int r = blockIdx.x * 8 + (threadIdx.x >> 5);
  if (r >= po[NE]) return;
  int e = 0;
#pragma unroll
  for (int q = 1; q < NE; ++q) if (r >= po[q]) e = q;
  int l = r - po[e];
  int c0 = (threadIdx.x & 31) * 32;
  short* dst = xg + (size_t)r * H_DIM + c0;
  if (l < rc[e]) {
    const float* src = x + (size_t)tokid[r] * H_DIM + c0;
#pragma unroll
    for (int j = 0; j < 4; ++j) *(short8*)(dst + j * 8) = pack8(src + j * 8);
  } else {
    short8 z = (short8)0;
#pragma unroll
    for (int j = 0; j < 4; ++j) *(short8*)(dst + j * 8) = z;
  }
}

// ---------------- convert weights f32 -> bf16 ------------------------------
#define W_ELEM ((size_t)NE * I_DIM * H_DIM)       // 23,068,672 per tensor
#define W_CHUNK (W_ELEM / 8)                      // 2,883,584
__global__ __launch_bounds__(256) void k_convert(const float* __restrict__ wg,
                                                 const float* __restrict__ wu,
                                                 const float* __restrict__ wd,
                                                 char* __restrict__ ws) {
  size_t idx = (size_t)blockIdx.x * 256 + threadIdx.x;
  size_t which = idx / W_CHUNK;
  size_t off = (idx % W_CHUNK) * 8;
  const float* src = (which == 0) ? wg : (which == 1) ? wu : wd;
  short* dst = (short*)(ws + ((which == 0) ? WS_WGB : (which == 1) ? WS_WUB : WS_WDB));
  *(short8*)(dst + off) = pack8(src + off);
}

// ---------------- FFN1: act = silu(xg@Wg^T) * (xg@Wu^T) --------------------
__global__ __launch_bounds__(256, 2) void k_ffn1(char* __restrict__ ws) {
  int mt = blockIdx.x, nt = blockIdx.y, e = blockIdx.z;
  const int* rc = (const int*)(ws + WS_ROUTE_CNT);
  int cnt = rc[e];
  if (mt * BM >= cnt) return;
  int poe = ((const int*)(ws + WS_PO))[e];
  const short* xg = (const short*)(ws + WS_XG);
  const short* wgb = (const short*)(ws + WS_WGB) + (size_t)e * I_DIM * H_DIM;
  const short* wub = (const short*)(ws + WS_WUB) + (size_t)e * I_DIM * H_DIM;
  short* act = (short*)(ws + WS_ACT);

  __shared__ __align__(16) short As[BM * BK];
  __shared__ __align__(16) short Bg[BN * BK];
  __shared__ __align__(16) short Bu[BN * BK];

  int tid = threadIdx.x, lane = tid & 63, wv = tid >> 6;
  int wr = (wv >> 1) * 64, wc = (wv & 1) * 64;
  int fr = lane & 15, kq = (lane >> 4) * 8;

  const short* aS[4]; const short* gS[4]; const short* uS[4];
  int ldo[4];
#pragma unroll
  for (int it = 0; it < 4; ++it) {
    int chunk = wv * 4 + it;
    int row = chunk * 8 + (lane >> 3);
    int col = (lane & 7) * 8;
    ldo[it] = chunk * 512 + lane * 8;               // shorts
    aS[it] = xg + (size_t)(poe + mt * BM + row) * H_DIM + col;
    gS[it] = wgb + (size_t)(nt * BN + row) * H_DIM + col;
    uS[it] = wub + (size_t)(nt * BN + row) * H_DIM + col;
  }

  f32x4 accg[4][4], accu[4][4];
  f32x4 z4 = {0.f, 0.f, 0.f, 0.f};
#pragma unroll
  for (int m = 0; m < 4; ++m)
#pragma unroll
    for (int n = 0; n < 4; ++n) { accg[m][n] = z4; accu[m][n] = z4; }

  for (int kk = 0; kk < H_DIM; kk += BK) {
#pragma unroll
    for (int it = 0; it < 4; ++it) {
      GLOAD16(aS[it] + kk, &As[ldo[it]]);
      GLOAD16(gS[it] + kk, &Bg[ldo[it]]);
      GLOAD16(uS[it] + kk, &Bu[ldo[it]]);
    }
    __syncthreads();
#pragma unroll
    for (int ks = 0; ks < 2; ++ks) {
      short8 af[4];
#pragma unroll
      for (int m = 0; m < 4; ++m)
        af[m] = *(const short8*)&As[(wr + m * 16 + fr) * BK + ks * 32 + kq];
#pragma unroll
      for (int n = 0; n < 4; ++n) {
        short8 bgf = *(const short8*)&Bg[(wc + n * 16 + fr) * BK + ks * 32 + kq];
        short8 buf_ = *(const short8*)&Bu[(wc + n * 16 + fr) * BK + ks * 32 + kq];
#pragma unroll
        for (int m = 0; m < 4; ++m) {
          accg[m][n] = __builtin_amdgcn_mfma_f32_16x16x32_bf16(af[m], bgf, accg[m][n], 0, 0, 0);
          accu[m][n] = __builtin_amdgcn_mfma_f32_16x16x32_bf16(af[m], buf_, accu[m][n], 0, 0, 0);
        }
      }
    }
    __syncthreads();
  }

#pragma unroll
  for (int m = 0; m < 4; ++m)
#pragma unroll
    for (int n = 0; n < 4; ++n)
#pragma unroll
      for (int j = 0; j < 4; ++j) {
        int row = wr + m * 16 + (lane >> 4) * 4 + j;
        int col = nt * BN + wc + n * 16 + fr;
        float g = accg[m][n][j];
        float u = accu[m][n][j];
        float a = g / (1.f + expf(-g)) * u;
        act[(size_t)(poe + mt * BM + row) * I_DIM + col] = f2bf(a);
      }
}

// ---------------- FFN2: y = act @ Wd^T, scaled scatter-add -----------------
__global__ __launch_bounds__(256, 2) void k_ffn2(float* __restrict__ out,
                                                 char* __restrict__ ws) {
  int mt = blockIdx.x, nt = blockIdx.y, e = blockIdx.z;
  const int* rc = (const int*)(ws + WS_ROUTE_CNT);
  int cnt = rc[e];
  if (mt * BM >= cnt) return;
  int poe = ((const int*)(ws + WS_PO))[e];
  const int* tokid = (const int*)(ws + WS_TOKID);
  const float* tokw = (const float*)(ws + WS_TOKW);
  const short* act = (const short*)(ws + WS_ACT);
  const short* wdb = (const short*)(ws + WS_WDB) + (size_t)e * H_DIM * I_DIM;

  __shared__ __align__(16) short As[BM * BK];
  __shared__ __align__(16) short Bd[BN * BK];

  int tid = threadIdx.x, lane = tid & 63, wv = tid >> 6;
  int wr = (wv >> 1) * 64, wc = (wv & 1) * 64;
  int fr = lane & 15, kq = (lane >> 4) * 8;

  const short* aS[4]; const short* dS[4];
  int ldo[4];
#pragma unroll
  for (int it = 0; it < 4; ++it) {
    int chunk = wv * 4 + it;
    int row = chunk * 8 + (lane >> 3);
    int col = (lane & 7) * 8;
    ldo[it] = chunk * 512 + lane * 8;
    aS[it] = act + (size_t)(poe + mt * BM + row) * I_DIM + col;
    dS[it] = wdb + (size_t)(nt * BN + row) * I_DIM + col;
  }

  f32x4 acc[4][4];
  f32x4 z4 = {0.f, 0.f, 0.f, 0.f};
#pragma unroll
  for (int m = 0; m < 4; ++m)
#pragma unroll
    for (int n = 0; n < 4; ++n) acc[m][n] = z4;

  for (int kk = 0; kk < I_DIM; kk += BK) {
#pragma unroll
    for (int it = 0; it < 4; ++it) {
      GLOAD16(aS[it] + kk, &As[ldo[it]]);
      GLOAD16(dS[it] + kk, &Bd[ldo[it]]);
    }
    __syncthreads();
#pragma unroll
    for (int ks = 0; ks < 2; ++ks) {
      short8 af[4];
#pragma unroll
      for (int m = 0; m < 4; ++m)
        af[m] = *(const short8*)&As[(wr + m * 16 + fr) * BK + ks * 32 + kq];
#pragma unroll
      for (int n = 0; n < 4; ++n) {
        short8 bdf = *(const short8*)&Bd[(wc + n * 16 + fr) * BK + ks * 32 + kq];
#pragma unroll
        for (int m = 0; m < 4; ++m)
          acc[m][n] = __builtin_amdgcn_mfma_f32_16x16x32_bf16(af[m], bdf, acc[m][n], 0, 0, 0);
      }
    }
    __syncthreads();
  }

#pragma unroll
  for (int m = 0; m < 4; ++m)
#pragma unroll
    for (int n = 0; n < 4; ++n)
#pragma unroll
      for (int j = 0; j < 4; ++j) {
        int row = wr + m * 16 + (lane >> 4) * 4 + j;
        int rg = mt * BM + row;
        if (rg < cnt) {
          int tok = tokid[poe + rg];
          float wgt = tokw[poe + rg];
          int col = nt * BN + wc + n * 16 + fr;
          atomicAdd(&out[(size_t)tok * H_DIM + col], wgt * acc[m][n][j]);
        }
      }
}

extern "C" void kernel_launch(void* const* d_in, const int* in_sizes, int n_in,
                              void* d_out, int out_size, void* d_ws, size_t ws_size,
                              hipStream_t stream) {
  const float* x  = (const float*)d_in[0];
  const float* gw = (const float*)d_in[1];
  const float* wg = (const float*)d_in[2];
  const float* wu = (const float*)d_in[3];
  const float* wd = (const float*)d_in[4];
  float* out = (float*)d_out;
  char* ws = (char*)d_ws;

  hipMemsetAsync(ws, 0, 256, stream);
  hipMemsetAsync(d_out, 0, (size_t)out_size * sizeof(float), stream);

  k_convert<<<(int)(3 * W_CHUNK / 256), 256, 0, stream>>>(wg, wu, wd, ws);
  k_router<<<T_TOK / 4, 256, 0, stream>>>(x, gw, ws);
  k_offsets<<<1, 64, 0, stream>>>(ws, out + (size_t)T_TOK * H_DIM);
  k_assign<<<T_TOK / 256, 256, 0, stream>>>(ws);
  k_gather<<<RMAX / 8, 256, 0, stream>>>(x, ws);
  k_ffn1<<<dim3(MT_MAX, I_DIM / BN, NE), 256, 0, stream>>>(ws);
  k_ffn2<<<dim3(MT_MAX, H_DIM / BN, NE), 256, 0, stream>>>(out, ws);
}